// Round 12
// baseline (324.533 us; speedup 1.0000x reference)
//
#include <hip/hip_runtime.h>

namespace {
constexpr int S  = 2048;
constexpr int D  = 64;
constexpr int BQ = 128;   // q-rows per block (32 per wave, 4 waves)
constexpr int BK = 64;
constexpr int NT = 256;
constexpr int NKT = S / BK;     // 32 key tiles

typedef short bf16x8 __attribute__((ext_vector_type(8)));
typedef float f32x4  __attribute__((ext_vector_type(4)));

__device__ inline unsigned short bf16c(float x) {
  __bf16 h = (__bf16)x;
  return __builtin_bit_cast(unsigned short, h);
}
__device__ inline unsigned pk2(float a, float b) {
  return (unsigned)bf16c(a) | ((unsigned)bf16c(b) << 16);
}
__device__ inline void gld_lds16(const void* g, void* l) {
  __builtin_amdgcn_global_load_lds(
      (const __attribute__((address_space(1))) unsigned int*)g,
      (__attribute__((address_space(3))) unsigned int*)l, 16, 0, 0);
}
#if __has_builtin(__builtin_amdgcn_exp2f)
__device__ inline float exp2v(float x) { return __builtin_amdgcn_exp2f(x); }
#else
__device__ inline float exp2v(float x) { return __expf(x * 0.6931471805599453f); }
#endif

// K row swizzle: for read rows rho = 32ks + 8*h2 + rr (+4), this equals
// rr | ((h2&1)<<2) == n16 & 7  -> read-side bank pattern identical to the
// proven conflict-free V pattern (bijective within every 8-lane group).
__device__ inline int kswz_of_row(int row) {
  return (row & 3) | (((row >> 3) & 1) << 2);
}

// softmax+pack: p = exp2(s) * m (mask is raw 0.0/1.0 float); pack to bf16.
// s0[r] = key base+r, s1[r] = key base+4+r; m0/m1 are the matching floats.
__device__ inline bf16x8 mk_pa(f32x4 s0, f32x4 s1, float4 m0, float4 m1) {
  uint4 u;
  u.x = pk2(exp2v(s0[0]) * m0.x, exp2v(s0[1]) * m0.y);
  u.y = pk2(exp2v(s0[2]) * m0.z, exp2v(s0[3]) * m0.w);
  u.z = pk2(exp2v(s1[0]) * m1.x, exp2v(s1[1]) * m1.y);
  u.w = pk2(exp2v(s1[2]) * m1.z, exp2v(s1[3]) * m1.w);
  return __builtin_bit_cast(bf16x8, u);
}

// ---- prep: K fp32 [bh][key][d] -> bf16, kswz granule-swizzled rows ----
__global__ __launch_bounds__(256) void prep_k(const float* __restrict__ K,
                                              unsigned short* __restrict__ Kws) {
  int gid = blockIdx.x * 256 + threadIdx.x;
  int row = gid >> 3;
  int g   = gid & 7;
  const float* src = K + (size_t)row * 64 + g * 8;
  float4 a = *(const float4*)src;
  float4 b = *(const float4*)(src + 4);
  uint4 w;
  w.x = pk2(a.x, a.y); w.y = pk2(a.z, a.w);
  w.z = pk2(b.x, b.y); w.w = pk2(b.z, b.w);
  *(uint4*)(Kws + (size_t)row * 64 + ((g ^ kswz_of_row(row)) * 8)) = w;
}

// ---- prep: V -> bf16 transposed tile-blocked [bh][kt][d][key], swizzled ----
// Two 64x64 tiles per 512-thread block; output written coalesced via LDS.
__global__ __launch_bounds__(512) void prep_v(const float* __restrict__ V,
                                              unsigned short* __restrict__ Vws) {
  __shared__ __align__(16) unsigned char smem[51200];
  const int t    = threadIdx.x;
  const int half = t >> 8;
  const int tsub = t & 255;
  const size_t tile = (size_t)blockIdx.x * 2 + half;
  float* tl = (float*)smem + half * (64 * 68);                        // 2x17408 B
  unsigned short* so = (unsigned short*)(smem + 34816) + half * 4096; // 2x8 KB
  const float* src = V + tile * (64 * 64);
#pragma unroll
  for (int rep = 0; rep < 4; ++rep) {
    int idx = tsub + rep * 256;
    int row = idx >> 4, d4 = idx & 15;
    float4 v = *(const float4*)(src + row * 64 + d4 * 4);
    *(float4*)(tl + row * 68 + d4 * 4) = v;
  }
  __syncthreads();
#pragma unroll
  for (int rep = 0; rep < 2; ++rep) {
    int d  = (tsub & 31) + rep * 32;  // conflict-free tl reads
    int kg = tsub >> 5;               // 0..7
    float x[8];
#pragma unroll
    for (int j = 0; j < 8; ++j) x[j] = tl[(kg * 8 + j) * 68 + d];
    uint4 w;
    w.x = pk2(x[0], x[1]); w.y = pk2(x[2], x[3]);
    w.z = pk2(x[4], x[5]); w.w = pk2(x[6], x[7]);
    *(uint4*)(so + d * 64 + ((kg ^ (d & 7)) * 8)) = w;
  }
  __syncthreads();
  unsigned short* dstT = Vws + tile * (64 * 64);
#pragma unroll
  for (int rep = 0; rep < 2; ++rep) {
    int i = tsub + rep * 256;          // 512 x 16B per tile, fully coalesced
    *(uint4*)(dstT + i * 8) = *(const uint4*)(so + i * 8);
  }
}

// ---- main attention: raw-mask fused (prep_m deleted) ----
// Each mask element is consumed by exactly one wave (no cross-block reuse),
// so the pack/repack through workspace was pure overhead. Lane (n16,quad)
// reads M[b][qg*32+n16(+16)][kt*64 + ks*32 + quad*8 + 0..7]; the 4 quads of
// an n16-group cover 128B contiguous -> full line utilization. Loads issue
// right after staging, consumed after the QK MFMA cluster (latency covered).
__global__ __launch_bounds__(NT, 4)
void attn3(const float* __restrict__ Qg, const float* __restrict__ Mg,
           const unsigned short* __restrict__ Kws,
           const unsigned short* __restrict__ Vws,
           float* __restrict__ Og) {
  __shared__ __align__(16) unsigned short sK[2][BK * D];   // 8 KB each
  __shared__ __align__(16) unsigned short sV[2][BK * D];

  const int t    = threadIdx.x;
  const int wave = t >> 6;                 // 0..3
  const int lane = t & 63;
  const int quad = lane >> 4;
  const int n16  = lane & 15;

  const int bh = blockIdx.y;
  const int b  = bh >> 4;
  const int q0 = blockIdx.x * BQ;

  const unsigned short* Kb = Kws + (size_t)bh * S * D;
  const unsigned short* Vb = Vws + (size_t)bh * S * D;

  // raw mask row pointers for this lane's two q-rows
  const float* MrA = Mg + ((size_t)b * S + (size_t)(q0 + wave * 32 + n16)) * S;
  const float* MrB = MrA + (size_t)16 * S;

  // K-read geometry: rows rho0 = 32ks + 8*h2 + rr (frag0), rho0+4 (frag1)
  const int h2 = n16 >> 2, rr = n16 & 3;
  const int krow0 = (8 * h2 + rr) * 64;         // shorts

  // shared granule offsets (kswz_of_row(rho) == n16&7 for K; row&7 == n16&7 for V)
  const int sw = n16 & 7;
  const int ga = (quad ^ sw) * 8;
  const int gb = ((quad + 4) ^ sw) * 8;

  // Q B-frags, pre-scaled by log2(e)/8 so scores feed v_exp (2^x) directly
  constexpr float QS = 0.18033688011112042f;
  const float* QbA = Qg + ((size_t)bh * S + q0 + wave * 32 + n16) * D;
  bf16x8 aqA[2], aqB[2];
#pragma unroll
  for (int ks = 0; ks < 2; ++ks) {
    const float* qp = QbA + ks * 32 + quad * 8;
    float4 x = *(const float4*)qp;
    float4 y = *(const float4*)(qp + 4);
    bf16x8 a;
    a[0] = (short)bf16c(x.x * QS); a[1] = (short)bf16c(x.y * QS);
    a[2] = (short)bf16c(x.z * QS); a[3] = (short)bf16c(x.w * QS);
    a[4] = (short)bf16c(y.x * QS); a[5] = (short)bf16c(y.y * QS);
    a[6] = (short)bf16c(y.z * QS); a[7] = (short)bf16c(y.w * QS);
    aqA[ks] = a;
    const float* qp2 = qp + 16 * D;
    float4 x2 = *(const float4*)qp2;
    float4 y2 = *(const float4*)(qp2 + 4);
    bf16x8 a2;
    a2[0] = (short)bf16c(x2.x * QS); a2[1] = (short)bf16c(x2.y * QS);
    a2[2] = (short)bf16c(x2.z * QS); a2[3] = (short)bf16c(x2.w * QS);
    a2[4] = (short)bf16c(y2.x * QS); a2[5] = (short)bf16c(y2.y * QS);
    a2[6] = (short)bf16c(y2.z * QS); a2[7] = (short)bf16c(y2.w * QS);
    aqB[ks] = a2;
  }

  bf16x8 ones;
#pragma unroll
  for (int i = 0; i < 8; ++i) ones[i] = (short)0x3F80;   // bf16 1.0

  f32x4 oA[4], oB[4];
#pragma unroll
  for (int nt = 0; nt < 4; ++nt) {
    oA[nt] = (f32x4){0.f, 0.f, 0.f, 0.f};
    oB[nt] = (f32x4){0.f, 0.f, 0.f, 0.f};
  }
  f32x4 rsA = (f32x4){0.f, 0.f, 0.f, 0.f};
  f32x4 rsB = (f32x4){0.f, 0.f, 0.f, 0.f};

  // prologue: stage tile 0 (2 KB per wave per tensor; 2 rounds)
  gld_lds16(Kb + wave * 512 + lane * 8, &sK[0][wave * 512]);
  gld_lds16(Kb + 2048 + wave * 512 + lane * 8, &sK[0][2048 + wave * 512]);
  gld_lds16(Vb + wave * 512 + lane * 8, &sV[0][wave * 512]);
  gld_lds16(Vb + 2048 + wave * 512 + lane * 8, &sV[0][2048 + wave * 512]);

#pragma unroll 2
  for (int kt = 0; kt < NKT; ++kt) {
    const int cur = kt & 1, nxt = cur ^ 1;
    __syncthreads();   // drains tile-kt loads; prior reads of buf[nxt] done

    if (kt + 1 < NKT) {
      const size_t gbase = (size_t)(kt + 1) * (BK * D);
      gld_lds16(Kb + gbase + wave * 512 + lane * 8, &sK[nxt][wave * 512]);
      gld_lds16(Kb + gbase + 2048 + wave * 512 + lane * 8,
                &sK[nxt][2048 + wave * 512]);
      gld_lds16(Vb + gbase + wave * 512 + lane * 8, &sV[nxt][wave * 512]);
      gld_lds16(Vb + gbase + 2048 + wave * 512 + lane * 8,
                &sV[nxt][2048 + wave * 512]);
    }

    // ---- raw mask loads for this tile (early issue; consumed after QK) ----
    const int kb = kt * 64 + quad * 8;
    float4 mA00 = *(const float4*)(MrA + kb);
    float4 mA01 = *(const float4*)(MrA + kb + 4);
    float4 mA10 = *(const float4*)(MrA + kb + 32);
    float4 mA11 = *(const float4*)(MrA + kb + 36);
    float4 mB00 = *(const float4*)(MrB + kb);
    float4 mB01 = *(const float4*)(MrB + kb + 4);
    float4 mB10 = *(const float4*)(MrB + kb + 32);
    float4 mB11 = *(const float4*)(MrB + kb + 36);

    // ---- S^T = K Q^T with permuted K rows; softmax lane-local ----
    bf16x8 paA[2], paB[2];
#pragma unroll
    for (int ks = 0; ks < 2; ++ks) {
      const unsigned short* base = &sK[cur][krow0 + ks * 2048];
      bf16x8 k0a = *(const bf16x8*)(base + ga);
      bf16x8 k0b = *(const bf16x8*)(base + gb);
      bf16x8 k1a = *(const bf16x8*)(base + 256 + ga);
      bf16x8 k1b = *(const bf16x8*)(base + 256 + gb);
      const f32x4 z = (f32x4){0.f, 0.f, 0.f, 0.f};

      f32x4 sA0 = __builtin_amdgcn_mfma_f32_16x16x32_bf16(k0a, aqA[0], z, 0, 0, 0);
      sA0 = __builtin_amdgcn_mfma_f32_16x16x32_bf16(k0b, aqA[1], sA0, 0, 0, 0);
      f32x4 sA1 = __builtin_amdgcn_mfma_f32_16x16x32_bf16(k1a, aqA[0], z, 0, 0, 0);
      sA1 = __builtin_amdgcn_mfma_f32_16x16x32_bf16(k1b, aqA[1], sA1, 0, 0, 0);
      paA[ks] = mk_pa(sA0, sA1, ks ? mA10 : mA00, ks ? mA11 : mA01);

      f32x4 sB0 = __builtin_amdgcn_mfma_f32_16x16x32_bf16(k0a, aqB[0], z, 0, 0, 0);
      sB0 = __builtin_amdgcn_mfma_f32_16x16x32_bf16(k0b, aqB[1], sB0, 0, 0, 0);
      f32x4 sB1 = __builtin_amdgcn_mfma_f32_16x16x32_bf16(k1a, aqB[0], z, 0, 0, 0);
      sB1 = __builtin_amdgcn_mfma_f32_16x16x32_bf16(k1b, aqB[1], sB1, 0, 0, 0);
      paB[ks] = mk_pa(sB0, sB1, ks ? mB10 : mB00, ks ? mB11 : mB01);
    }

    // ---- rowsum via ones-MFMA: every lane gets full denominator for its q ----
    rsA = __builtin_amdgcn_mfma_f32_16x16x32_bf16(ones, paA[0], rsA, 0, 0, 0);
    rsA = __builtin_amdgcn_mfma_f32_16x16x32_bf16(ones, paA[1], rsA, 0, 0, 0);
    rsB = __builtin_amdgcn_mfma_f32_16x16x32_bf16(ones, paB[0], rsB, 0, 0, 0);
    rsB = __builtin_amdgcn_mfma_f32_16x16x32_bf16(ones, paB[1], rsB, 0, 0, 0);

    // ---- O^T += V^T P^T : V frags shared by both q-groups ----
#pragma unroll
    for (int nt = 0; nt < 4; ++nt) {
      const int row = nt * 16 + n16;
      bf16x8 v0 = *(const bf16x8*)(sV[cur] + row * 64 + ga);
      bf16x8 v1 = *(const bf16x8*)(sV[cur] + row * 64 + gb);
      oA[nt] = __builtin_amdgcn_mfma_f32_16x16x32_bf16(v0, paA[0], oA[nt], 0, 0, 0);
      oA[nt] = __builtin_amdgcn_mfma_f32_16x16x32_bf16(v1, paA[1], oA[nt], 0, 0, 0);
      oB[nt] = __builtin_amdgcn_mfma_f32_16x16x32_bf16(v0, paB[0], oB[nt], 0, 0, 0);
      oB[nt] = __builtin_amdgcn_mfma_f32_16x16x32_bf16(v1, paB[1], oB[nt], 0, 0, 0);
    }
  }

  // ---- normalize + store (lane writes d-contiguous float4 runs of its own q) ----
  const float invA = 1.0f / (rsA[0] + 1e-8f);
  const float invB = 1.0f / (rsB[0] + 1e-8f);
  float* OA = Og + ((size_t)bh * S + q0 + wave * 32 + n16) * D;
#pragma unroll
  for (int nt = 0; nt < 4; ++nt) {
    float4 wa = make_float4(oA[nt][0] * invA, oA[nt][1] * invA,
                            oA[nt][2] * invA, oA[nt][3] * invA);
    *(float4*)(OA + nt * 16 + quad * 4) = wa;
    float4 wb = make_float4(oB[nt][0] * invB, oB[nt][1] * invB,
                            oB[nt][2] * invB, oB[nt][3] * invB);
    *(float4*)(OA + 16 * D + nt * 16 + quad * 4) = wb;
  }
}
} // namespace

extern "C" void kernel_launch(void* const* d_in, const int* in_sizes, int n_in,
                              void* d_out, int out_size, void* d_ws, size_t ws_size,
                              hipStream_t stream) {
  const float* Q = (const float*)d_in[0];
  const float* K = (const float*)d_in[1];
  const float* V = (const float*)d_in[2];
  const float* M = (const float*)d_in[3];
  float* O = (float*)d_out;

  unsigned short* Kws = (unsigned short*)d_ws;
  unsigned short* Vws = Kws + (size_t)64 * S * D;                 // +16.78 MB

  prep_k<<<dim3(64 * S * D / 8 / 256), 256, 0, stream>>>(K, Kws);
  prep_v<<<dim3(64 * NKT / 2), 512, 0, stream>>>(V, Vws);
  attn3<<<dim3(S / BQ, 64), NT, 0, stream>>>(Q, M, Kws, Vws, O);
}